// Round 13
// baseline (219.023 us; speedup 1.0000x reference)
//
#include <hip/hip_runtime.h>
#include <hip/hip_bf16.h>
#include <cstdint>

#define B_      2
#define L_      2048
#define DM_     1024
#define H_      16
#define DQ_     64
#define LN_EPS  1e-5f
#define QSCALE  0.1803368801111204f   // 0.125 * log2(e): P = exp2(Q'.K)

typedef unsigned short u16;
typedef unsigned int   u32;
typedef __attribute__((ext_vector_type(8)))  short short8;
typedef __attribute__((ext_vector_type(4)))  unsigned short u16x4;
typedef __attribute__((ext_vector_type(4)))  unsigned int   u32x4;
typedef __attribute__((ext_vector_type(4)))  float f32x4;
typedef __attribute__((ext_vector_type(16))) float f32x16;

__device__ __forceinline__ u16 f2b(float f) {
  __hip_bfloat16 h = __float2bfloat16(f);
  return *reinterpret_cast<u16*>(&h);
}
__device__ __forceinline__ u32 pk2(float lo, float hi) {
  return (u32)f2b(lo) | ((u32)f2b(hi) << 16);
}

// async global->LDS, 16B per lane. lds ptr wave-uniform; data at lds+lane*16.
__device__ __forceinline__ void gl_lds16(const void* g, void* l) {
  auto gp = reinterpret_cast<const __attribute__((address_space(1))) unsigned int*>(
      reinterpret_cast<uintptr_t>(g));
  auto lp = reinterpret_cast<__attribute__((address_space(3))) unsigned int*>(
      reinterpret_cast<uintptr_t>(l));
  __builtin_amdgcn_global_load_lds(gp, lp, 16, 0, 0);
}

// frag read from unpadded stride-64 tile with XOR swizzle (chunk ^= row&7).
__device__ __forceinline__ short8 frag8(const u16* base, int row, int lchunk) {
  return *(const short8*)(base + row * 64 + ((lchunk ^ (row & 7)) << 3));
}

// ---------------------------------------------------------------------------
// Prep (fused): cast x -> bf16; transpose/cast w_qkv -> wt; wo -> wot.
// ---------------------------------------------------------------------------
__global__ __launch_bounds__(256) void prep_all(
    const float* __restrict__ x, const float* __restrict__ wq,
    const float* __restrict__ wk, const float* __restrict__ wv,
    const float* __restrict__ wo, u16* __restrict__ xb,
    u16* __restrict__ wt, u16* __restrict__ wot) {
  __shared__ float Ls[64][65];
  const int t = threadIdx.x;
  const int bx = blockIdx.x;
  if (bx < 4096) {
    int i = bx * 256 + t;
    float4 v = ((const float4*)x)[i];
    u16x4 o = { f2b(v.x), f2b(v.y), f2b(v.z), f2b(v.w) };
    *(u16x4*)(xb + (size_t)i * 4) = o;
  } else if (bx < 4096 + 768) {
    int b2 = bx - 4096;
    int mt = b2 & 15, h = (b2 >> 4) & 15, wh = b2 >> 8;
    const float* in = ((wh == 0) ? wq : (wh == 1) ? wk : wv) + (size_t)h * DM_ * DQ_;
    #pragma unroll
    for (int i = 0; i < 16; ++i) {
      int idx = i * 256 + t, r = idx >> 6, c = idx & 63;
      Ls[r][c] = in[(size_t)(mt * 64 + r) * DQ_ + c];
    }
    __syncthreads();
    u16* outb = wt + (size_t)(wh * H_ + h) * DQ_ * DM_;
    #pragma unroll
    for (int i = 0; i < 16; ++i) {
      int idx = i * 256 + t, q = idx >> 6, mm = idx & 63;
      outb[(size_t)q * DM_ + mt * 64 + mm] = f2b(Ls[mm][q]);
    }
  } else {
    int b3 = bx - 4864;
    int mt = b3 & 15, kt = b3 >> 4;
    #pragma unroll
    for (int i = 0; i < 16; ++i) {
      int idx = i * 256 + t, r = idx >> 6, c = idx & 63;
      Ls[r][c] = wo[(size_t)(kt * 64 + r) * DM_ + mt * 64 + c];
    }
    __syncthreads();
    #pragma unroll
    for (int i = 0; i < 16; ++i) {
      int idx = i * 256 + t, mm = idx >> 6, kk = idx & 63;
      wot[(size_t)(mt * 64 + mm) * DM_ + kt * 64 + kk] = f2b(Ls[kk][mm]);
    }
  }
}

// ---------------------------------------------------------------------------
// Kernel 1: fused QKV GEMM [4096x1024]*[1024x3072], 256x128 tiles on
// 32x32x16 MFMA (2 row-blocks/wave; B-frags shared across row-blocks ->
// 24 LDS reads per 32 MFMAs). Direct global epilogue stores (no LDS tile).
// Q pre-scaled by QSCALE; V stored [b][h][d][l'] with key bits 2<->3 swapped.
// grid (24 n-tiles, 16 m-tiles) = 384 blocks.
// ---------------------------------------------------------------------------
__global__ __launch_bounds__(256) void qkv_big(const u16* __restrict__ xb,
    const u16* __restrict__ wt, u16* __restrict__ Q, u16* __restrict__ K,
    u16* __restrict__ Vtg) {
  const int nt = blockIdx.x, mt = blockIdx.y;
  __shared__ __align__(16) u16 As_[256 * 64];   // 32 KB: x rows
  __shared__ __align__(16) u16 Bs_[128 * 64];   // 16 KB: wt rows (n-major)
  const int t = threadIdx.x, w = t >> 6, lane = t & 63;
  const int c = lane & 31, lsel = lane >> 5;
  const int r8 = lane >> 3, lc = (lane & 7) ^ r8;
  const int row0 = mt * 256, n0 = nt * 128;

  const u16* gA = xb + (size_t)(row0 + w * 64 + r8) * DM_ + lc * 8;
  const u16* gB = wt + (size_t)(n0  + w * 32 + r8) * DM_ + lc * 8;
  u16* lA = As_ + (w * 64) * 64;
  u16* lB = Bs_ + (w * 32) * 64;

  f32x16 zz = {0.f,0.f,0.f,0.f,0.f,0.f,0.f,0.f,0.f,0.f,0.f,0.f,0.f,0.f,0.f,0.f};
  f32x16 acc[2][4] = {{zz, zz, zz, zz}, {zz, zz, zz, zz}};

  for (int k0 = 0; k0 < DM_; k0 += 64) {
    #pragma unroll
    for (int i = 0; i < 8; ++i)
      gl_lds16(gA + (size_t)i * 8 * DM_ + k0, lA + i * 8 * 64);
    #pragma unroll
    for (int i = 0; i < 4; ++i)
      gl_lds16(gB + (size_t)i * 8 * DM_ + k0, lB + i * 8 * 64);
    __syncthreads();
    #pragma unroll
    for (int km = 0; km < 4; ++km) {
      short8 a0 = frag8(As_, w * 64 + c,      (km << 1) | lsel);
      short8 a1 = frag8(As_, w * 64 + 32 + c, (km << 1) | lsel);
      #pragma unroll
      for (int ct = 0; ct < 4; ++ct) {
        short8 b = frag8(Bs_, ct * 32 + c, (km << 1) | lsel);
        acc[0][ct] = __builtin_amdgcn_mfma_f32_32x32x16_bf16(a0, b, acc[0][ct], 0, 0, 0);
        acc[1][ct] = __builtin_amdgcn_mfma_f32_32x32x16_bf16(a1, b, acc[1][ct], 0, 0, 0);
      }
    }
    __syncthreads();
  }

  // ---- epilogue: direct global stores from 32x32 C-layout ----
  const int wh = nt >> 3;                  // 0:Q 1:K 2:V (block-uniform, 128|1024)
  const float oscale = (wh == 0) ? QSCALE : 1.0f;
  u16* qk = (wh == 0) ? Q : K;
  #pragma unroll
  for (int rb = 0; rb < 2; ++rb)
    #pragma unroll
    for (int ct = 0; ct < 4; ++ct)
      #pragma unroll
      for (int r = 0; r < 16; ++r) {
        int m_row = row0 + w * 64 + rb * 32 + (r & 3) + 8 * (r >> 2) + 4 * lsel;
        int bb = m_row >> 11, l = m_row & 2047;
        int n = (n0 & 1023) + ct * 32 + c;
        int hh = n >> 6, d = n & 63;
        u16 val = f2b(acc[rb][ct][r] * oscale);
        if (wh == 2) {
          int lp = (l & ~12) | ((l & 4) << 1) | ((l & 8) >> 1);
          Vtg[((size_t)(bb * H_ + hh) * DQ_ + d) * L_ + lp] = val;
        } else {
          qk[((size_t)(bb * H_ + hh) * L_ + l) * DQ_ + d] = val;
        }
      }
}

// ---------------------------------------------------------------------------
// Kernel 2: flash attention, Q-tile 256 via 8-wave blocks (32 q-rows/wave).
// Double-buffered K/V DMA prefetch, ONE barrier per K-tile; P in registers
// (Vt key-permuted). grid (8,16,2)=256 blocks. (unchanged from R12)
// ---------------------------------------------------------------------------
__global__ __launch_bounds__(512) void attn_mfma(const u16* __restrict__ Q,
    const u16* __restrict__ K, const u16* __restrict__ Vtg, u16* __restrict__ att) {
  const int qt = blockIdx.x, h = blockIdx.y, b = blockIdx.z;
  __shared__ __align__(16) u16 Qs_[256 * 64];        // 32 KB
  __shared__ __align__(16) u16 Ks_[2][64 * 64];      // 16 KB
  __shared__ __align__(16) u16 Vt_[2][64 * 64];      // 16 KB
  const int t = threadIdx.x, w = t >> 6, lane = t & 63;
  const int c = lane & 31, lsel = lane >> 5;
  const int r8 = lane >> 3, lc = (lane & 7) ^ r8;
  const size_t bh  = (size_t)(b * H_ + h) * L_ * DQ_;
  const size_t bhv = (size_t)(b * H_ + h) * DQ_ * L_;

  // Q tile 256x64 via DMA: wave w stages rows [w*32, w*32+32)
  const u16* gQ = Q + bh + (size_t)(qt * 256 + w * 32 + r8) * DQ_ + lc * 8;
  #pragma unroll
  for (int i = 0; i < 4; ++i) gl_lds16(gQ + (size_t)i * 8 * DQ_, Qs_ + (w * 32 + i * 8) * 64);

  // wave w stages K rows [w*8, w*8+8) and Vt rows [w*8, w*8+8) of each tile
  const u16* gK = K   + bh  + (size_t)(w * 8 + r8) * DQ_ + lc * 8;
  const u16* gV = Vtg + bhv + (size_t)(w * 8 + r8) * L_  + lc * 8;

  // prime: K/V tile 0 into buffer 0
  gl_lds16(gK, Ks_[0] + w * 8 * 64);
  gl_lds16(gV, Vt_[0] + w * 8 * 64);
  __syncthreads();                          // Q (and tile 0) landed
  short8 qb[4];                             // B-frag: B[k=d][n=q], fixed
  #pragma unroll
  for (int km = 0; km < 4; ++km) qb[km] = frag8(Qs_, w * 32 + c, (km << 1) | lsel);

  f32x16 zz = {0.f,0.f,0.f,0.f,0.f,0.f,0.f,0.f,0.f,0.f,0.f,0.f,0.f,0.f,0.f,0.f};
  f32x16 oacc0 = zz, oacc1 = zz, lacc = zz;
  const short one_bf = (short)0x3F80;
  short8 ones = {one_bf, one_bf, one_bf, one_bf, one_bf, one_bf, one_bf, one_bf};

  for (int kt = 0; kt < L_ / 64; ++kt) {
    const int cur = kt & 1;
    __syncthreads();     // (a) DMA into buf[cur] drained  (b) prev reads of buf[cur] done

    if (kt + 1 < L_ / 64) {                 // prefetch tile kt+1 into buf[1-cur]
      const int nxt = 1 - cur;
      gl_lds16(gK + (size_t)(kt + 1) * 64 * DQ_, Ks_[nxt] + w * 8 * 64);
      gl_lds16(gV + (size_t)(kt + 1) * 64,       Vt_[nxt] + w * 8 * 64);
    }

    // S^T = K * Q'^T, then P = exp2(S') packed straight into A-frags (regs)
    u32x4 paw[4];
    #pragma unroll
    for (int kb = 0; kb < 2; ++kb) {
      f32x16 s = zz;
      #pragma unroll
      for (int km = 0; km < 4; ++km) {
        short8 ka = frag8(Ks_[cur], kb * 32 + c, (km << 1) | lsel);
        s = __builtin_amdgcn_mfma_f32_32x32x16_bf16(ka, qb[km], s, 0, 0, 0);
      }
      #pragma unroll
      for (int F = 0; F < 2; ++F) {
        u32x4 pw;
        #pragma unroll
        for (int i = 0; i < 4; ++i) {
          float p0 = __builtin_amdgcn_exp2f(s[8 * F + 2 * i]);
          float p1 = __builtin_amdgcn_exp2f(s[8 * F + 2 * i + 1]);
          pw[i] = __builtin_amdgcn_perm(__float_as_uint(p1), __float_as_uint(p0), 0x07060302u);
        }
        paw[2 * kb + F] = pw;
      }
    }

    // O += P V ; ones-column accumulates row sums (P from registers)
    #pragma unroll
    for (int km = 0; km < 4; ++km) {
      short8 pa  = *reinterpret_cast<const short8*>(&paw[km]);
      short8 vb0 = frag8(Vt_[cur], c,      (km << 1) | lsel);
      short8 vb1 = frag8(Vt_[cur], 32 + c, (km << 1) | lsel);
      oacc0 = __builtin_amdgcn_mfma_f32_32x32x16_bf16(pa, vb0, oacc0, 0, 0, 0);
      oacc1 = __builtin_amdgcn_mfma_f32_32x32x16_bf16(pa, vb1, oacc1, 0, 0, 0);
      lacc  = __builtin_amdgcn_mfma_f32_32x32x16_bf16(pa, ones, lacc, 0, 0, 0);
    }
  }

  const int qrow_base = qt * 256 + w * 32;
  #pragma unroll
  for (int r = 0; r < 16; ++r) {
    int qr = (r & 3) + 8 * (r >> 2) + 4 * lsel;
    float inv = 1.0f / lacc[r];
    size_t base = (size_t)(b * L_ + qrow_base + qr) * DM_ + h * DQ_;
    att[base + c]      = f2b(oacc0[r] * inv);
    att[base + 32 + c] = f2b(oacc1[r] * inv);
  }
}

// ---------------------------------------------------------------------------
// Kernel 3: output projection [4096x1024]*[1024x1024], 128x64 tiles, DMA
// staging, fp32 out. (unchanged from R12)
// ---------------------------------------------------------------------------
__global__ __launch_bounds__(256) void oproj_big(const u16* __restrict__ A,
    const u16* __restrict__ wot, float* __restrict__ out) {
  const int nt = blockIdx.x, mt = blockIdx.y;
  __shared__ __align__(16) u16 As_[128 * 64];
  __shared__ __align__(16) u16 Bs_[64 * 64];
  const int t = threadIdx.x, w = t >> 6, lane = t & 63;
  const int lx = lane & 15, lq = lane >> 4;
  const int row0 = mt * 128, n0 = nt * 64;
  const int r8 = lane >> 3, lc = (lane & 7) ^ r8;

  const u16* gA = A   + (size_t)(row0 + w * 32 + r8) * DM_ + lc * 8;
  const u16* gB = wot + (size_t)(n0  + w * 16 + r8) * DM_ + lc * 8;
  u16* lA = As_ + (w * 32) * 64;
  u16* lB = Bs_ + (w * 16) * 64;

  f32x4 z = {0.f, 0.f, 0.f, 0.f};
  f32x4 acc[2][4];
  #pragma unroll
  for (int mb = 0; mb < 2; ++mb)
    #pragma unroll
    for (int nb = 0; nb < 4; ++nb) acc[mb][nb] = z;

  for (int k0 = 0; k0 < DM_; k0 += 64) {
    #pragma unroll
    for (int i = 0; i < 4; ++i)
      gl_lds16(gA + (size_t)i * 8 * DM_ + k0, lA + i * 8 * 64);
    #pragma unroll
    for (int i = 0; i < 2; ++i)
      gl_lds16(gB + (size_t)i * 8 * DM_ + k0, lB + i * 8 * 64);
    __syncthreads();
    short8 af[2][2];
    #pragma unroll
    for (int mb = 0; mb < 2; ++mb)
      #pragma unroll
      for (int kh = 0; kh < 2; ++kh)
        af[mb][kh] = frag8(As_, w * 32 + mb * 16 + lx, (kh << 2) | lq);
    #pragma unroll
    for (int nb = 0; nb < 4; ++nb) {
      short8 b0 = frag8(Bs_, nb * 16 + lx, lq);
      short8 b1 = frag8(Bs_, nb * 16 + lx, 4 | lq);
      acc[0][nb] = __builtin_amdgcn_mfma_f32_16x16x32_bf16(af[0][0], b0, acc[0][nb], 0, 0, 0);
      acc[0][nb] = __builtin_amdgcn_mfma_f32_16x16x32_bf16(af[0][1], b1, acc[0][nb], 0, 0, 0);
      acc[1][nb] = __builtin_amdgcn_mfma_f32_16x16x32_bf16(af[1][0], b0, acc[1][nb], 0, 0, 0);
      acc[1][nb] = __builtin_amdgcn_mfma_f32_16x16x32_bf16(af[1][1], b1, acc[1][nb], 0, 0, 0);
    }
    __syncthreads();
  }
  #pragma unroll
  for (int mb = 0; mb < 2; ++mb)
    #pragma unroll
    for (int nb = 0; nb < 4; ++nb)
      #pragma unroll
      for (int r = 0; r < 4; ++r) {
        int row = row0 + w * 32 + mb * 16 + lq * 4 + r;
        out[(size_t)row * DM_ + n0 + nb * 16 + lx] = acc[mb][nb][r];
      }
}

// ---------------------------------------------------------------------------
// Kernel 4: residual + LayerNorm (in place on `out`).
// ---------------------------------------------------------------------------
__global__ __launch_bounds__(256) void resid_ln(
    const float* __restrict__ x, const float* __restrict__ gamma,
    const float* __restrict__ beta, float* __restrict__ out) {
  const int row = blockIdx.x;
  const int t   = threadIdx.x;
  const float4* xp = (const float4*)(x   + (size_t)row * DM_);
  float4*       yp = (float4*)      (out + (size_t)row * DM_);

  float4 xv = xp[t];
  float4 av = yp[t];
  float y0 = xv.x + av.x, y1 = xv.y + av.y, y2 = xv.z + av.z, y3 = xv.w + av.w;

  float s  = y0 + y1 + y2 + y3;
  float s2 = y0 * y0 + y1 * y1 + y2 * y2 + y3 * y3;
  #pragma unroll
  for (int off = 32; off > 0; off >>= 1) {
    s  += __shfl_xor(s,  off, 64);
    s2 += __shfl_xor(s2, off, 64);
  }
  __shared__ float red[8];
  const int wave = t >> 6, lane = t & 63;
  if (lane == 0) { red[wave] = s; red[4 + wave] = s2; }
  __syncthreads();
  s  = red[0] + red[1] + red[2] + red[3];
  s2 = red[4] + red[5] + red[6] + red[7];

  const float mean = s * (1.f / DM_);
  const float var  = s2 * (1.f / DM_) - mean * mean;
  const float inv  = rsqrtf(var + LN_EPS);

  const float4 g  = ((const float4*)gamma)[t];
  const float4 bt = ((const float4*)beta)[t];
  float4 r;
  r.x = (y0 - mean) * inv * g.x + bt.x;
  r.y = (y1 - mean) * inv * g.y + bt.y;
  r.z = (y2 - mean) * inv * g.z + bt.z;
  r.w = (y3 - mean) * inv * g.w + bt.w;
  yp[t] = r;
}

// ---------------------------------------------------------------------------
extern "C" void kernel_launch(void* const* d_in, const int* in_sizes, int n_in,
                              void* d_out, int out_size, void* d_ws, size_t ws_size,
                              hipStream_t stream) {
  const float* x     = (const float*)d_in[0];
  const float* wq    = (const float*)d_in[1];
  const float* wk    = (const float*)d_in[2];
  const float* wv    = (const float*)d_in[3];
  const float* wo    = (const float*)d_in[4];
  const float* gamma = (const float*)d_in[5];
  const float* beta  = (const float*)d_in[6];
  float* out = (float*)d_out;

  char* ws = (char*)d_ws;
  u16* xb  = (u16*)ws;                          // [ 0, 8) MB  [4096][1024]
  u16* Qb  = (u16*)(ws + ((size_t)8  << 20));   // [ 8,16) MB  [b][h][l][d]  (pre-scaled)
  u16* Kb  = (u16*)(ws + ((size_t)16 << 20));   // [16,24) MB  [b][h][l][d]
  u16* Vtg = (u16*)(ws + ((size_t)24 << 20));   // [24,32) MB  [b][h][d][l'] (transposed, key-permuted)
  u16* wt  = (u16*)(ws + ((size_t)32 << 20));   // [32,38) MB  [3][h][q][m] = [3072][1024]
  u16* wot = (u16*)(ws + ((size_t)38 << 20));   // [38,40) MB  [m][h*64+q]  = [1024][1024]
  u16* att = (u16*)(ws + ((size_t)40 << 20));   // [40,48) MB  [b*l][h*64+d]

  prep_all <<<5120, 256, 0, stream>>>(x, wq, wk, wv, wo, xb, wt, wot);
  qkv_big  <<<dim3(24, 16),    256, 0, stream>>>(xb, wt, Qb, Kb, Vtg);
  attn_mfma<<<dim3(L_ / 256, H_, B_), 512, 0, stream>>>(Qb, Kb, Vtg, att);
  oproj_big<<<dim3(16, 32),    256, 0, stream>>>(att, wot, out);
  resid_ln <<<B_ * L_, 256, 0, stream>>>(x, gamma, beta, out);
}

// Round 14
// 182.654 us; speedup vs baseline: 1.1991x; 1.1991x over previous
//
#include <hip/hip_runtime.h>
#include <hip/hip_bf16.h>
#include <cstdint>

#define B_      2
#define L_      2048
#define DM_     1024
#define H_      16
#define DQ_     64
#define LN_EPS  1e-5f
#define QSCALE  0.1803368801111204f   // 0.125 * log2(e): P = exp2(Q'.K)

typedef unsigned short u16;
typedef unsigned int   u32;
typedef __attribute__((ext_vector_type(8)))  short short8;
typedef __attribute__((ext_vector_type(4)))  unsigned short u16x4;
typedef __attribute__((ext_vector_type(4)))  unsigned int   u32x4;
typedef __attribute__((ext_vector_type(4)))  float f32x4;
typedef __attribute__((ext_vector_type(16))) float f32x16;

__device__ __forceinline__ u16 f2b(float f) {
  __hip_bfloat16 h = __float2bfloat16(f);
  return *reinterpret_cast<u16*>(&h);
}
__device__ __forceinline__ u32 pk2(float lo, float hi) {
  return (u32)f2b(lo) | ((u32)f2b(hi) << 16);
}

// async global->LDS, 16B per lane. lds ptr wave-uniform; data at lds+lane*16.
__device__ __forceinline__ void gl_lds16(const void* g, void* l) {
  auto gp = reinterpret_cast<const __attribute__((address_space(1))) unsigned int*>(
      reinterpret_cast<uintptr_t>(g));
  auto lp = reinterpret_cast<__attribute__((address_space(3))) unsigned int*>(
      reinterpret_cast<uintptr_t>(l));
  __builtin_amdgcn_global_load_lds(gp, lp, 16, 0, 0);
}

// frag read from unpadded stride-64 tile with XOR swizzle (chunk ^= row&7).
__device__ __forceinline__ short8 frag8(const u16* base, int row, int lchunk) {
  return *(const short8*)(base + row * 64 + ((lchunk ^ (row & 7)) << 3));
}

// ---------------------------------------------------------------------------
// Prep (fused): cast x -> bf16; transpose/cast w_qkv -> wt; wo -> wot.
// ---------------------------------------------------------------------------
__global__ __launch_bounds__(256) void prep_all(
    const float* __restrict__ x, const float* __restrict__ wq,
    const float* __restrict__ wk, const float* __restrict__ wv,
    const float* __restrict__ wo, u16* __restrict__ xb,
    u16* __restrict__ wt, u16* __restrict__ wot) {
  __shared__ float Ls[64][65];
  const int t = threadIdx.x;
  const int bx = blockIdx.x;
  if (bx < 4096) {
    int i = bx * 256 + t;
    float4 v = ((const float4*)x)[i];
    u16x4 o = { f2b(v.x), f2b(v.y), f2b(v.z), f2b(v.w) };
    *(u16x4*)(xb + (size_t)i * 4) = o;
  } else if (bx < 4096 + 768) {
    int b2 = bx - 4096;
    int mt = b2 & 15, h = (b2 >> 4) & 15, wh = b2 >> 8;
    const float* in = ((wh == 0) ? wq : (wh == 1) ? wk : wv) + (size_t)h * DM_ * DQ_;
    #pragma unroll
    for (int i = 0; i < 16; ++i) {
      int idx = i * 256 + t, r = idx >> 6, c = idx & 63;
      Ls[r][c] = in[(size_t)(mt * 64 + r) * DQ_ + c];
    }
    __syncthreads();
    u16* outb = wt + (size_t)(wh * H_ + h) * DQ_ * DM_;
    #pragma unroll
    for (int i = 0; i < 16; ++i) {
      int idx = i * 256 + t, q = idx >> 6, mm = idx & 63;
      outb[(size_t)q * DM_ + mt * 64 + mm] = f2b(Ls[mm][q]);
    }
  } else {
    int b3 = bx - 4864;
    int mt = b3 & 15, kt = b3 >> 4;
    #pragma unroll
    for (int i = 0; i < 16; ++i) {
      int idx = i * 256 + t, r = idx >> 6, c = idx & 63;
      Ls[r][c] = wo[(size_t)(kt * 64 + r) * DM_ + mt * 64 + c];
    }
    __syncthreads();
    #pragma unroll
    for (int i = 0; i < 16; ++i) {
      int idx = i * 256 + t, mm = idx >> 6, kk = idx & 63;
      wot[(size_t)(mt * 64 + mm) * DM_ + kt * 64 + kk] = f2b(Ls[kk][mm]);
    }
  }
}

// ---------------------------------------------------------------------------
// Kernel 1: fused QKV GEMM [4096x1024]*[1024x3072], 128x128 tiles, DMA staged
// (R12 shape: 768 blocks, 3/CU). Waves remapped to a 2x2 grid of 64x64
// sub-tiles: 16 LDS frag reads per 32 MFMAs (was 20). Epilogue via padded
// LDS tile -> coalesced bursts. Q pre-scaled; V stored [b][h][d][l'] with
// key bits 2<->3 swapped (attn P-register trick).
// ---------------------------------------------------------------------------
__global__ __launch_bounds__(256) void qkv_big(const u16* __restrict__ xb,
    const u16* __restrict__ wt, u16* __restrict__ Q, u16* __restrict__ K,
    u16* __restrict__ Vtg) {
  const int nt = blockIdx.x, mt = blockIdx.y;
  __shared__ __align__(16) u16 SH[128 * 136];
  u16* As_ = SH;
  u16* Bs_ = SH + 8192;
  const int t = threadIdx.x, w = t >> 6, lane = t & 63;
  const int lx = lane & 15, lq = lane >> 4;
  const int row0 = mt * 128, n0 = nt * 128;
  const int r8 = lane >> 3, lc = (lane & 7) ^ r8;
  const int wr = (w >> 1) * 64, wc = (w & 1) * 64;   // wave's 64x64 sub-tile

  const u16* gA = xb + (size_t)(row0 + w * 32 + r8) * DM_ + lc * 8;
  const u16* gB = wt + (size_t)(n0  + w * 32 + r8) * DM_ + lc * 8;
  u16* lA = As_ + (w * 32) * 64;
  u16* lB = Bs_ + (w * 32) * 64;

  f32x4 z = {0.f, 0.f, 0.f, 0.f};
  f32x4 acc[4][4];
  #pragma unroll
  for (int mb = 0; mb < 4; ++mb)
    #pragma unroll
    for (int nb = 0; nb < 4; ++nb) acc[mb][nb] = z;

  for (int k0 = 0; k0 < DM_; k0 += 64) {
    #pragma unroll
    for (int i = 0; i < 4; ++i) {
      gl_lds16(gA + (size_t)i * 8 * DM_ + k0, lA + i * 8 * 64);
      gl_lds16(gB + (size_t)i * 8 * DM_ + k0, lB + i * 8 * 64);
    }
    __syncthreads();
    short8 af[4][2];
    #pragma unroll
    for (int mb = 0; mb < 4; ++mb)
      #pragma unroll
      for (int kh = 0; kh < 2; ++kh)
        af[mb][kh] = frag8(As_, wr + mb * 16 + lx, (kh << 2) | lq);
    #pragma unroll
    for (int nb = 0; nb < 4; ++nb) {
      short8 b0 = frag8(Bs_, wc + nb * 16 + lx, lq);
      short8 b1 = frag8(Bs_, wc + nb * 16 + lx, 4 | lq);
      #pragma unroll
      for (int mb = 0; mb < 4; ++mb) {
        acc[mb][nb] = __builtin_amdgcn_mfma_f32_16x16x32_bf16(af[mb][0], b0, acc[mb][nb], 0, 0, 0);
        acc[mb][nb] = __builtin_amdgcn_mfma_f32_16x16x32_bf16(af[mb][1], b1, acc[mb][nb], 0, 0, 0);
      }
    }
    __syncthreads();
  }

  // ---- epilogue: C -> LDS (136-padded) -> coalesced global bursts ----
  const int wh = n0 >> 10;                 // 0:Q 1:K 2:V (uniform per block)
  const float oscale = (wh == 0) ? QSCALE : 1.0f;
  const int bb = row0 >> 11, l0 = row0 & 2047;
  const int hd0 = n0 & 1023;
  u16* Ep = SH;                            // 128 x 136

  if (wh != 2) {
    #pragma unroll
    for (int mb = 0; mb < 4; ++mb)
      #pragma unroll
      for (int nb = 0; nb < 4; ++nb)
        #pragma unroll
        for (int r = 0; r < 4; ++r) {
          int l = wr + mb * 16 + lq * 4 + r;
          Ep[l * 136 + wc + nb * 16 + lx] = f2b(acc[mb][nb][r] * oscale);
        }
    __syncthreads();
    u16* outp = (wh == 0) ? Q : K;
    #pragma unroll
    for (int hs = 0; hs < 2; ++hs) {       // each head: contiguous 16KB (128 rows x 64 d)
      const int hh = (hd0 >> 6) + hs;
      u16* gbase = outp + ((size_t)(bb * H_ + hh) * L_ + l0) * DQ_;
      #pragma unroll
      for (int it = 0; it < 4; ++it) {
        int u = it * 256 + t;
        int l = u >> 3, chunk = u & 7;
        *(uint4*)(gbase + u * 8) = *(const uint4*)&Ep[l * 136 + hs * 64 + chunk * 8];
      }
    }
  } else {
    // V: transpose to Ep[n(d)][l'], l' = l with bits 2<->3 swapped (PV trick)
    #pragma unroll
    for (int mb = 0; mb < 4; ++mb)
      #pragma unroll
      for (int nb = 0; nb < 4; ++nb) {
        int l = wr + mb * 16 + lq * 4;
        int lp = (l & ~12) | ((l & 4) << 1) | ((l & 8) >> 1);
        uint2 pv = { pk2(acc[mb][nb][0], acc[mb][nb][1]),
                     pk2(acc[mb][nb][2], acc[mb][nb][3]) };
        *(uint2*)&Ep[(wc + nb * 16 + lx) * 136 + lp] = pv;
      }
    __syncthreads();
    #pragma unroll
    for (int it = 0; it < 8; ++it) {       // 2048 uint4; 16 lanes cover one d-row's 256B run
      int v = it * 256 + t;
      int dloc = v >> 4, chunk = v & 15;
      int hh = (hd0 + dloc) >> 6, dd = (hd0 + dloc) & 63;
      u16* g = Vtg + ((size_t)(bb * H_ + hh) * DQ_ + dd) * L_ + l0 + chunk * 8;
      *(uint4*)g = *(const uint4*)&Ep[dloc * 136 + chunk * 8];
    }
  }
}

// ---------------------------------------------------------------------------
// Kernel 2: flash attention, Q-tile 256 via 8-wave blocks (32 q-rows/wave).
// Double-buffered K/V DMA prefetch, ONE barrier per K-tile; P in registers
// (Vt key-permuted). grid (8,16,2)=256 blocks. (unchanged from R12)
// ---------------------------------------------------------------------------
__global__ __launch_bounds__(512) void attn_mfma(const u16* __restrict__ Q,
    const u16* __restrict__ K, const u16* __restrict__ Vtg, u16* __restrict__ att) {
  const int qt = blockIdx.x, h = blockIdx.y, b = blockIdx.z;
  __shared__ __align__(16) u16 Qs_[256 * 64];        // 32 KB
  __shared__ __align__(16) u16 Ks_[2][64 * 64];      // 16 KB
  __shared__ __align__(16) u16 Vt_[2][64 * 64];      // 16 KB
  const int t = threadIdx.x, w = t >> 6, lane = t & 63;
  const int c = lane & 31, lsel = lane >> 5;
  const int r8 = lane >> 3, lc = (lane & 7) ^ r8;
  const size_t bh  = (size_t)(b * H_ + h) * L_ * DQ_;
  const size_t bhv = (size_t)(b * H_ + h) * DQ_ * L_;

  // Q tile 256x64 via DMA: wave w stages rows [w*32, w*32+32)
  const u16* gQ = Q + bh + (size_t)(qt * 256 + w * 32 + r8) * DQ_ + lc * 8;
  #pragma unroll
  for (int i = 0; i < 4; ++i) gl_lds16(gQ + (size_t)i * 8 * DQ_, Qs_ + (w * 32 + i * 8) * 64);

  // wave w stages K rows [w*8, w*8+8) and Vt rows [w*8, w*8+8) of each tile
  const u16* gK = K   + bh  + (size_t)(w * 8 + r8) * DQ_ + lc * 8;
  const u16* gV = Vtg + bhv + (size_t)(w * 8 + r8) * L_  + lc * 8;

  // prime: K/V tile 0 into buffer 0
  gl_lds16(gK, Ks_[0] + w * 8 * 64);
  gl_lds16(gV, Vt_[0] + w * 8 * 64);
  __syncthreads();                          // Q (and tile 0) landed
  short8 qb[4];                             // B-frag: B[k=d][n=q], fixed
  #pragma unroll
  for (int km = 0; km < 4; ++km) qb[km] = frag8(Qs_, w * 32 + c, (km << 1) | lsel);

  f32x16 zz = {0.f,0.f,0.f,0.f,0.f,0.f,0.f,0.f,0.f,0.f,0.f,0.f,0.f,0.f,0.f,0.f};
  f32x16 oacc0 = zz, oacc1 = zz, lacc = zz;
  const short one_bf = (short)0x3F80;
  short8 ones = {one_bf, one_bf, one_bf, one_bf, one_bf, one_bf, one_bf, one_bf};

  for (int kt = 0; kt < L_ / 64; ++kt) {
    const int cur = kt & 1;
    __syncthreads();     // (a) DMA into buf[cur] drained  (b) prev reads of buf[cur] done

    if (kt + 1 < L_ / 64) {                 // prefetch tile kt+1 into buf[1-cur]
      const int nxt = 1 - cur;
      gl_lds16(gK + (size_t)(kt + 1) * 64 * DQ_, Ks_[nxt] + w * 8 * 64);
      gl_lds16(gV + (size_t)(kt + 1) * 64,       Vt_[nxt] + w * 8 * 64);
    }

    // S^T = K * Q'^T, then P = exp2(S') packed straight into A-frags (regs)
    u32x4 paw[4];
    #pragma unroll
    for (int kb = 0; kb < 2; ++kb) {
      f32x16 s = zz;
      #pragma unroll
      for (int km = 0; km < 4; ++km) {
        short8 ka = frag8(Ks_[cur], kb * 32 + c, (km << 1) | lsel);
        s = __builtin_amdgcn_mfma_f32_32x32x16_bf16(ka, qb[km], s, 0, 0, 0);
      }
      #pragma unroll
      for (int F = 0; F < 2; ++F) {
        u32x4 pw;
        #pragma unroll
        for (int i = 0; i < 4; ++i) {
          float p0 = __builtin_amdgcn_exp2f(s[8 * F + 2 * i]);
          float p1 = __builtin_amdgcn_exp2f(s[8 * F + 2 * i + 1]);
          pw[i] = __builtin_amdgcn_perm(__float_as_uint(p1), __float_as_uint(p0), 0x07060302u);
        }
        paw[2 * kb + F] = pw;
      }
    }

    // O += P V ; ones-column accumulates row sums (P from registers)
    #pragma unroll
    for (int km = 0; km < 4; ++km) {
      short8 pa  = *reinterpret_cast<const short8*>(&paw[km]);
      short8 vb0 = frag8(Vt_[cur], c,      (km << 1) | lsel);
      short8 vb1 = frag8(Vt_[cur], 32 + c, (km << 1) | lsel);
      oacc0 = __builtin_amdgcn_mfma_f32_32x32x16_bf16(pa, vb0, oacc0, 0, 0, 0);
      oacc1 = __builtin_amdgcn_mfma_f32_32x32x16_bf16(pa, vb1, oacc1, 0, 0, 0);
      lacc  = __builtin_amdgcn_mfma_f32_32x32x16_bf16(pa, ones, lacc, 0, 0, 0);
    }
  }

  const int qrow_base = qt * 256 + w * 32;
  #pragma unroll
  for (int r = 0; r < 16; ++r) {
    int qr = (r & 3) + 8 * (r >> 2) + 4 * lsel;
    float inv = 1.0f / lacc[r];
    size_t base = (size_t)(b * L_ + qrow_base + qr) * DM_ + h * DQ_;
    att[base + c]      = f2b(oacc0[r] * inv);
    att[base + 32 + c] = f2b(oacc1[r] * inv);
  }
}

// ---------------------------------------------------------------------------
// Kernel 3: output projection [4096x1024]*[1024x1024], 128x64 tiles, DMA
// staging, fp32 out. (unchanged from R12)
// ---------------------------------------------------------------------------
__global__ __launch_bounds__(256) void oproj_big(const u16* __restrict__ A,
    const u16* __restrict__ wot, float* __restrict__ out) {
  const int nt = blockIdx.x, mt = blockIdx.y;
  __shared__ __align__(16) u16 As_[128 * 64];
  __shared__ __align__(16) u16 Bs_[64 * 64];
  const int t = threadIdx.x, w = t >> 6, lane = t & 63;
  const int lx = lane & 15, lq = lane >> 4;
  const int row0 = mt * 128, n0 = nt * 64;
  const int r8 = lane >> 3, lc = (lane & 7) ^ r8;

  const u16* gA = A   + (size_t)(row0 + w * 32 + r8) * DM_ + lc * 8;
  const u16* gB = wot + (size_t)(n0  + w * 16 + r8) * DM_ + lc * 8;
  u16* lA = As_ + (w * 32) * 64;
  u16* lB = Bs_ + (w * 16) * 64;

  f32x4 z = {0.f, 0.f, 0.f, 0.f};
  f32x4 acc[2][4];
  #pragma unroll
  for (int mb = 0; mb < 2; ++mb)
    #pragma unroll
    for (int nb = 0; nb < 4; ++nb) acc[mb][nb] = z;

  for (int k0 = 0; k0 < DM_; k0 += 64) {
    #pragma unroll
    for (int i = 0; i < 4; ++i)
      gl_lds16(gA + (size_t)i * 8 * DM_ + k0, lA + i * 8 * 64);
    #pragma unroll
    for (int i = 0; i < 2; ++i)
      gl_lds16(gB + (size_t)i * 8 * DM_ + k0, lB + i * 8 * 64);
    __syncthreads();
    short8 af[2][2];
    #pragma unroll
    for (int mb = 0; mb < 2; ++mb)
      #pragma unroll
      for (int kh = 0; kh < 2; ++kh)
        af[mb][kh] = frag8(As_, w * 32 + mb * 16 + lx, (kh << 2) | lq);
    #pragma unroll
    for (int nb = 0; nb < 4; ++nb) {
      short8 b0 = frag8(Bs_, nb * 16 + lx, lq);
      short8 b1 = frag8(Bs_, nb * 16 + lx, 4 | lq);
      acc[0][nb] = __builtin_amdgcn_mfma_f32_16x16x32_bf16(af[0][0], b0, acc[0][nb], 0, 0, 0);
      acc[0][nb] = __builtin_amdgcn_mfma_f32_16x16x32_bf16(af[0][1], b1, acc[0][nb], 0, 0, 0);
      acc[1][nb] = __builtin_amdgcn_mfma_f32_16x16x32_bf16(af[1][0], b0, acc[1][nb], 0, 0, 0);
      acc[1][nb] = __builtin_amdgcn_mfma_f32_16x16x32_bf16(af[1][1], b1, acc[1][nb], 0, 0, 0);
    }
    __syncthreads();
  }
  #pragma unroll
  for (int mb = 0; mb < 2; ++mb)
    #pragma unroll
    for (int nb = 0; nb < 4; ++nb)
      #pragma unroll
      for (int r = 0; r < 4; ++r) {
        int row = row0 + w * 32 + mb * 16 + lq * 4 + r;
        out[(size_t)row * DM_ + n0 + nb * 16 + lx] = acc[mb][nb][r];
      }
}

// ---------------------------------------------------------------------------
// Kernel 4: residual + LayerNorm (in place on `out`).
// ---------------------------------------------------------------------------
__global__ __launch_bounds__(256) void resid_ln(
    const float* __restrict__ x, const float* __restrict__ gamma,
    const float* __restrict__ beta, float* __restrict__ out) {
  const int row = blockIdx.x;
  const int t   = threadIdx.x;
  const float4* xp = (const float4*)(x   + (size_t)row * DM_);
  float4*       yp = (float4*)      (out + (size_t)row * DM_);

  float4 xv = xp[t];
  float4 av = yp[t];
  float y0 = xv.x + av.x, y1 = xv.y + av.y, y2 = xv.z + av.z, y3 = xv.w + av.w;

  float s  = y0 + y1 + y2 + y3;
  float s2 = y0 * y0 + y1 * y1 + y2 * y2 + y3 * y3;
  #pragma unroll
  for (int off = 32; off > 0; off >>= 1) {
    s  += __shfl_xor(s,  off, 64);
    s2 += __shfl_xor(s2, off, 64);
  }
  __shared__ float red[8];
  const int wave = t >> 6, lane = t & 63;
  if (lane == 0) { red[wave] = s; red[4 + wave] = s2; }
  __syncthreads();
  s  = red[0] + red[1] + red[2] + red[3];
  s2 = red[4] + red[5] + red[6] + red[7];

  const float mean = s * (1.f / DM_);
  const float var  = s2 * (1.f / DM_) - mean * mean;
  const float inv  = rsqrtf(var + LN_EPS);

  const float4 g  = ((const float4*)gamma)[t];
  const float4 bt = ((const float4*)beta)[t];
  float4 r;
  r.x = (y0 - mean) * inv * g.x + bt.x;
  r.y = (y1 - mean) * inv * g.y + bt.y;
  r.z = (y2 - mean) * inv * g.z + bt.z;
  r.w = (y3 - mean) * inv * g.w + bt.w;
  yp[t] = r;
}

// ---------------------------------------------------------------------------
extern "C" void kernel_launch(void* const* d_in, const int* in_sizes, int n_in,
                              void* d_out, int out_size, void* d_ws, size_t ws_size,
                              hipStream_t stream) {
  const float* x     = (const float*)d_in[0];
  const float* wq    = (const float*)d_in[1];
  const float* wk    = (const float*)d_in[2];
  const float* wv    = (const float*)d_in[3];
  const float* wo    = (const float*)d_in[4];
  const float* gamma = (const float*)d_in[5];
  const float* beta  = (const float*)d_in[6];
  float* out = (float*)d_out;

  char* ws = (char*)d_ws;
  u16* xb  = (u16*)ws;                          // [ 0, 8) MB  [4096][1024]
  u16* Qb  = (u16*)(ws + ((size_t)8  << 20));   // [ 8,16) MB  [b][h][l][d]  (pre-scaled)
  u16* Kb  = (u16*)(ws + ((size_t)16 << 20));   // [16,24) MB  [b][h][l][d]
  u16* Vtg = (u16*)(ws + ((size_t)24 << 20));   // [24,32) MB  [b][h][d][l'] (transposed, key-permuted)
  u16* wt  = (u16*)(ws + ((size_t)32 << 20));   // [32,38) MB  [3][h][q][m] = [3072][1024]
  u16* wot = (u16*)(ws + ((size_t)38 << 20));   // [38,40) MB  [m][h*64+q]  = [1024][1024]
  u16* att = (u16*)(ws + ((size_t)40 << 20));   // [40,48) MB  [b*l][h*64+d]

  prep_all <<<5120, 256, 0, stream>>>(x, wq, wk, wv, wo, xb, wt, wot);
  qkv_big  <<<dim3(24, 32),    256, 0, stream>>>(xb, wt, Qb, Kb, Vtg);
  attn_mfma<<<dim3(L_ / 256, H_, B_), 512, 0, stream>>>(Qb, Kb, Vtg, att);
  oproj_big<<<dim3(16, 32),    256, 0, stream>>>(att, wot, out);
  resid_ln <<<B_ * L_, 256, 0, stream>>>(x, gamma, beta, out);
}